// Round 1
// baseline (218.730 us; speedup 1.0000x reference)
//
#include <hip/hip_runtime.h>
#include <hip/hip_bf16.h>

// MIoU (buggy-source-faithful): result = popcount(classes 1..20 present in y_pred) / 21.
// y_true is ignored by the reference. Pure memory-bound presence scan over 64 MiB int32.

#define NUM_CLASSES 21

__global__ __launch_bounds__(256) void miou_scan(const int* __restrict__ yp,
                                                 unsigned int* __restrict__ mask_ws,
                                                 int n4) {
    // n4 = number of int4 vectors
    const int4* __restrict__ yp4 = (const int4*)yp;
    unsigned int m = 0u;
    int idx = blockIdx.x * blockDim.x + threadIdx.x;
    int stride = gridDim.x * blockDim.x;
    for (int i = idx; i < n4; i += stride) {
        int4 v = yp4[i];
        m |= (1u << v.x);
        m |= (1u << v.y);
        m |= (1u << v.z);
        m |= (1u << v.w);
    }
    // wave-64 OR reduction (butterfly)
    #pragma unroll
    for (int off = 32; off >= 1; off >>= 1) {
        m |= __shfl_xor(m, off, 64);
    }
    // one atomic per wave
    if ((threadIdx.x & 63) == 0) {
        atomicOr(mask_ws, m);
    }
}

__global__ void miou_finalize(const unsigned int* __restrict__ mask_ws,
                              float* __restrict__ out) {
    // classes 1..NUM_CLASSES-1 -> bits 1..20
    unsigned int m = *mask_ws & 0x001FFFFEu;
    out[0] = (float)__popc(m) / (float)NUM_CLASSES;
}

extern "C" void kernel_launch(void* const* d_in, const int* in_sizes, int n_in,
                              void* d_out, int out_size, void* d_ws, size_t ws_size,
                              hipStream_t stream) {
    const int* y_pred = (const int*)d_in[0];
    // d_in[1] (y_true) is dead in the reference.
    float* out = (float*)d_out;
    unsigned int* mask_ws = (unsigned int*)d_ws;

    int n = in_sizes[0];          // 16,777,216 (divisible by 4)
    int n4 = n >> 2;

    hipMemsetAsync(mask_ws, 0, sizeof(unsigned int), stream);

    const int block = 256;
    const int grid = 2048;        // 8 blocks/CU worth of waves; grid-stride covers n4
    miou_scan<<<grid, block, 0, stream>>>(y_pred, mask_ws, n4);
    miou_finalize<<<1, 1, 0, stream>>>(mask_ws, out);
}

// Round 2
// 133.792 us; speedup vs baseline: 1.6348x; 1.6348x over previous
//
#include <hip/hip_runtime.h>
#include <hip/hip_bf16.h>

// MIoU (buggy-source-faithful): result = popcount(classes 1..20 present in y_pred) / 21.
// y_true is dead in the reference. Pure presence scan over 64 MiB of int32.
//
// R1 post-mortem: per-wave atomicOr to a single address serialized (~31 cyc/op
// x 8192 ops ~= 107 us). This version: per-block plain store + tiny reduce
// kernel; zero atomics, zero memset.

#define NUM_CLASSES 21
#define SCAN_GRID 2048
#define SCAN_BLOCK 256

__global__ __launch_bounds__(SCAN_BLOCK) void miou_scan(
        const int* __restrict__ yp,
        unsigned int* __restrict__ block_masks,
        int n4) {
    const int4* __restrict__ yp4 = (const int4*)yp;
    unsigned int m = 0u;
    int idx = blockIdx.x * blockDim.x + threadIdx.x;
    int stride = gridDim.x * blockDim.x;
    // 4M int4 / 512K threads = 8 iters; unroll so all loads issue up-front.
    #pragma unroll 8
    for (int i = idx; i < n4; i += stride) {
        int4 v = yp4[i];
        m |= (1u << v.x);
        m |= (1u << v.y);
        m |= (1u << v.z);
        m |= (1u << v.w);
    }
    // wave-64 OR butterfly
    #pragma unroll
    for (int off = 32; off >= 1; off >>= 1) {
        m |= __shfl_xor(m, off, 64);
    }
    __shared__ unsigned int wmask[SCAN_BLOCK / 64];
    if ((threadIdx.x & 63) == 0) {
        wmask[threadIdx.x >> 6] = m;
    }
    __syncthreads();
    if (threadIdx.x == 0) {
        block_masks[blockIdx.x] = wmask[0] | wmask[1] | wmask[2] | wmask[3];
    }
}

__global__ __launch_bounds__(256) void miou_finalize(
        const unsigned int* __restrict__ block_masks,
        float* __restrict__ out,
        int nblocks) {
    unsigned int m = 0u;
    for (int i = threadIdx.x; i < nblocks; i += blockDim.x) {
        m |= block_masks[i];
    }
    #pragma unroll
    for (int off = 32; off >= 1; off >>= 1) {
        m |= __shfl_xor(m, off, 64);
    }
    __shared__ unsigned int wmask[4];
    if ((threadIdx.x & 63) == 0) {
        wmask[threadIdx.x >> 6] = m;
    }
    __syncthreads();
    if (threadIdx.x == 0) {
        unsigned int t = (wmask[0] | wmask[1] | wmask[2] | wmask[3]) & 0x001FFFFEu;
        out[0] = (float)__popc(t) / (float)NUM_CLASSES;
    }
}

extern "C" void kernel_launch(void* const* d_in, const int* in_sizes, int n_in,
                              void* d_out, int out_size, void* d_ws, size_t ws_size,
                              hipStream_t stream) {
    const int* y_pred = (const int*)d_in[0];
    // d_in[1] (y_true) is dead in the reference.
    float* out = (float*)d_out;
    unsigned int* block_masks = (unsigned int*)d_ws;  // SCAN_GRID dwords

    int n = in_sizes[0];   // 16,777,216
    int n4 = n >> 2;

    miou_scan<<<SCAN_GRID, SCAN_BLOCK, 0, stream>>>(y_pred, block_masks, n4);
    miou_finalize<<<1, 256, 0, stream>>>(block_masks, out, SCAN_GRID);
}

// Round 3
// 133.155 us; speedup vs baseline: 1.6427x; 1.0048x over previous
//
#include <hip/hip_runtime.h>
#include <hip/hip_bf16.h>

// MIoU (buggy-source-faithful): result = popcount(classes 1..20 present in y_pred) / 21.
// y_true is dead in the reference. Pure presence scan over 64 MiB of int32.
//
// R1 post-mortem: same-address atomicOr serialized (~31 cyc/op) -> 107 us scan.
// R2 post-mortem: atomic-free version works; total 134 us of which ~110 us is
//   harness-fixed (256 MiB ws 0xAA poison @40 us + input restore copies).
//   Scan ~20 us vs ~11 us floor -> flatten the loop, oversubscribe waves.

#define NUM_CLASSES 21
#define SCAN_GRID 4096
#define SCAN_BLOCK 256

__global__ __launch_bounds__(SCAN_BLOCK) void miou_scan(
        const int* __restrict__ yp,
        unsigned int* __restrict__ block_masks,
        int n4) {
    const int4* __restrict__ yp4 = (const int4*)yp;
    const int idx = blockIdx.x * blockDim.x + threadIdx.x;
    const int stride = gridDim.x * blockDim.x;
    unsigned int m = 0u;

    if (n4 == 4 * stride) {
        // Fast path (taken at the bench shape): 4 independent 16B loads,
        // no loop-carried dependency, no per-iter branch.
        int4 v0 = yp4[idx];
        int4 v1 = yp4[idx + stride];
        int4 v2 = yp4[idx + 2 * stride];
        int4 v3 = yp4[idx + 3 * stride];
        m = (1u << v0.x) | (1u << v0.y) | (1u << v0.z) | (1u << v0.w)
          | (1u << v1.x) | (1u << v1.y) | (1u << v1.z) | (1u << v1.w)
          | (1u << v2.x) | (1u << v2.y) | (1u << v2.z) | (1u << v2.w)
          | (1u << v3.x) | (1u << v3.y) | (1u << v3.z) | (1u << v3.w);
    } else {
        for (int i = idx; i < n4; i += stride) {
            int4 v = yp4[i];
            m |= (1u << v.x) | (1u << v.y) | (1u << v.z) | (1u << v.w);
        }
    }

    // wave-64 OR butterfly
    #pragma unroll
    for (int off = 32; off >= 1; off >>= 1) {
        m |= __shfl_xor(m, off, 64);
    }
    __shared__ unsigned int wmask[SCAN_BLOCK / 64];
    if ((threadIdx.x & 63) == 0) {
        wmask[threadIdx.x >> 6] = m;
    }
    __syncthreads();
    if (threadIdx.x == 0) {
        block_masks[blockIdx.x] = wmask[0] | wmask[1] | wmask[2] | wmask[3];
    }
}

__global__ __launch_bounds__(256) void miou_finalize(
        const unsigned int* __restrict__ block_masks,
        float* __restrict__ out,
        int nblocks) {
    unsigned int m = 0u;
    for (int i = threadIdx.x; i < nblocks; i += blockDim.x) {
        m |= block_masks[i];
    }
    #pragma unroll
    for (int off = 32; off >= 1; off >>= 1) {
        m |= __shfl_xor(m, off, 64);
    }
    __shared__ unsigned int wmask[4];
    if ((threadIdx.x & 63) == 0) {
        wmask[threadIdx.x >> 6] = m;
    }
    __syncthreads();
    if (threadIdx.x == 0) {
        unsigned int t = (wmask[0] | wmask[1] | wmask[2] | wmask[3]) & 0x001FFFFEu;
        out[0] = (float)__popc(t) / (float)NUM_CLASSES;
    }
}

extern "C" void kernel_launch(void* const* d_in, const int* in_sizes, int n_in,
                              void* d_out, int out_size, void* d_ws, size_t ws_size,
                              hipStream_t stream) {
    const int* y_pred = (const int*)d_in[0];
    // d_in[1] (y_true) is dead in the reference.
    float* out = (float*)d_out;
    unsigned int* block_masks = (unsigned int*)d_ws;  // SCAN_GRID dwords

    int n = in_sizes[0];   // 16,777,216
    int n4 = n >> 2;

    miou_scan<<<SCAN_GRID, SCAN_BLOCK, 0, stream>>>(y_pred, block_masks, n4);
    miou_finalize<<<1, 256, 0, stream>>>(block_masks, out, SCAN_GRID);
}

// Round 4
// 132.345 us; speedup vs baseline: 1.6527x; 1.0061x over previous
//
#include <hip/hip_runtime.h>
#include <hip/hip_bf16.h>

// MIoU (buggy-source-faithful): result = popcount(classes 1..20 present in y_pred) / 21.
// y_true is dead in the reference. Pure presence scan over 64 MiB of int32.
//
// R1 post-mortem: same-address atomicOr serialized (~31 cyc/op) -> 107 us scan.
// R2 post-mortem: atomic-free -> total 134 us; decomposition says scan ~23 us
//   (2.8 TB/s) vs harness fill at 6.5 TB/s.
// R3 post-mortem: flattening the 4-load grid-stride loop was neutral -> not
//   load-issue-bound. Suspect stream locality + residency churn.
// R4: wave-contiguous 32 KB spans, 8 outstanding dwordx4/wave, single
//   residency pass (2048 blocks x 4 waves = 32 waves/CU exactly).

#define NUM_CLASSES 21
#define SCAN_GRID 2048
#define SCAN_BLOCK 256
#define WAVES_PER_BLOCK (SCAN_BLOCK / 64)
#define VEC_PER_WAVE 512   // 8 loads x 64 lanes, int4 units (32 KB per wave)

__global__ __launch_bounds__(SCAN_BLOCK) void miou_scan(
        const int* __restrict__ yp,
        unsigned int* __restrict__ block_masks,
        int n4) {
    const int4* __restrict__ yp4 = (const int4*)yp;
    const int lane = threadIdx.x & 63;
    const int wave_in_block = threadIdx.x >> 6;
    const int gwave = blockIdx.x * WAVES_PER_BLOCK + wave_in_block;
    unsigned int m = 0u;

    if (n4 == SCAN_GRID * WAVES_PER_BLOCK * VEC_PER_WAVE) {
        // Fast path (bench shape): wave reads a contiguous 32 KB span as
        // 8 independent lane-contiguous 16B loads -> sequential DRAM streams.
        const int base = gwave * VEC_PER_WAVE + lane;
        int4 v0 = yp4[base + 0 * 64];
        int4 v1 = yp4[base + 1 * 64];
        int4 v2 = yp4[base + 2 * 64];
        int4 v3 = yp4[base + 3 * 64];
        int4 v4 = yp4[base + 4 * 64];
        int4 v5 = yp4[base + 5 * 64];
        int4 v6 = yp4[base + 6 * 64];
        int4 v7 = yp4[base + 7 * 64];
        m  = (1u << v0.x) | (1u << v0.y) | (1u << v0.z) | (1u << v0.w);
        m |= (1u << v1.x) | (1u << v1.y) | (1u << v1.z) | (1u << v1.w);
        m |= (1u << v2.x) | (1u << v2.y) | (1u << v2.z) | (1u << v2.w);
        m |= (1u << v3.x) | (1u << v3.y) | (1u << v3.z) | (1u << v3.w);
        m |= (1u << v4.x) | (1u << v4.y) | (1u << v4.z) | (1u << v4.w);
        m |= (1u << v5.x) | (1u << v5.y) | (1u << v5.z) | (1u << v5.w);
        m |= (1u << v6.x) | (1u << v6.y) | (1u << v6.z) | (1u << v6.w);
        m |= (1u << v7.x) | (1u << v7.y) | (1u << v7.z) | (1u << v7.w);
    } else {
        const int idx = blockIdx.x * blockDim.x + threadIdx.x;
        const int stride = gridDim.x * blockDim.x;
        for (int i = idx; i < n4; i += stride) {
            int4 v = yp4[i];
            m |= (1u << v.x) | (1u << v.y) | (1u << v.z) | (1u << v.w);
        }
    }

    // wave-64 OR butterfly
    #pragma unroll
    for (int off = 32; off >= 1; off >>= 1) {
        m |= __shfl_xor(m, off, 64);
    }
    __shared__ unsigned int wmask[WAVES_PER_BLOCK];
    if (lane == 0) {
        wmask[wave_in_block] = m;
    }
    __syncthreads();
    if (threadIdx.x == 0) {
        block_masks[blockIdx.x] = wmask[0] | wmask[1] | wmask[2] | wmask[3];
    }
}

__global__ __launch_bounds__(256) void miou_finalize(
        const unsigned int* __restrict__ block_masks,
        float* __restrict__ out,
        int nblocks) {
    unsigned int m = 0u;
    for (int i = threadIdx.x; i < nblocks; i += blockDim.x) {
        m |= block_masks[i];
    }
    #pragma unroll
    for (int off = 32; off >= 1; off >>= 1) {
        m |= __shfl_xor(m, off, 64);
    }
    __shared__ unsigned int wmask[4];
    if ((threadIdx.x & 63) == 0) {
        wmask[threadIdx.x >> 6] = m;
    }
    __syncthreads();
    if (threadIdx.x == 0) {
        unsigned int t = (wmask[0] | wmask[1] | wmask[2] | wmask[3]) & 0x001FFFFEu;
        out[0] = (float)__popc(t) / (float)NUM_CLASSES;
    }
}

extern "C" void kernel_launch(void* const* d_in, const int* in_sizes, int n_in,
                              void* d_out, int out_size, void* d_ws, size_t ws_size,
                              hipStream_t stream) {
    const int* y_pred = (const int*)d_in[0];
    // d_in[1] (y_true) is dead in the reference.
    float* out = (float*)d_out;
    unsigned int* block_masks = (unsigned int*)d_ws;  // SCAN_GRID dwords

    int n = in_sizes[0];   // 16,777,216
    int n4 = n >> 2;

    miou_scan<<<SCAN_GRID, SCAN_BLOCK, 0, stream>>>(y_pred, block_masks, n4);
    miou_finalize<<<1, 256, 0, stream>>>(block_masks, out, SCAN_GRID);
}

// Round 6
// 128.418 us; speedup vs baseline: 1.7033x; 1.0306x over previous
//
#include <hip/hip_runtime.h>
#include <hip/hip_bf16.h>

// MIoU (buggy-source-faithful): result = popcount(classes 1..20 present in y_pred) / 21.
// y_true is dead in the reference. Pure presence scan over 64 MiB of int32.
//
// R1 post-mortem: same-address atomicOr serialized (~31 cyc/op) -> 107 us scan.
// R2 post-mortem: atomic-free -> total 134 us; scan ~22 us (3.2 TB/s read).
// R3 post-mortem: flat 4-load version neutral -> not load-issue-bound.
// R4 post-mortem: wave-contiguous single-pass neutral -> memory-path ceiling,
//   not scheduling. Read caps at 3.2 TB/s while harness fill writes at 6.6.
// R5 post-mortem: __builtin_nontemporal_load rejects HIP int4 (struct type);
//   needs a native clang ext_vector_type. Same experiment, fixed type.

#define NUM_CLASSES 21
#define SCAN_GRID 2048
#define SCAN_BLOCK 256
#define WAVES_PER_BLOCK (SCAN_BLOCK / 64)
#define VEC_PER_WAVE 512   // 8 loads x 64 lanes, int4 units (32 KB per wave)

typedef int vint4 __attribute__((ext_vector_type(4)));

__global__ __launch_bounds__(SCAN_BLOCK) void miou_scan(
        const int* __restrict__ yp,
        unsigned int* __restrict__ block_masks,
        int n4) {
    const vint4* __restrict__ yp4 = (const vint4*)yp;
    const int lane = threadIdx.x & 63;
    const int wave_in_block = threadIdx.x >> 6;
    const int gwave = blockIdx.x * WAVES_PER_BLOCK + wave_in_block;
    unsigned int m = 0u;

    if (n4 == SCAN_GRID * WAVES_PER_BLOCK * VEC_PER_WAVE) {
        // Fast path (bench shape): wave reads a contiguous 32 KB span as
        // 8 independent lane-contiguous non-temporal 16B loads.
        const int base = gwave * VEC_PER_WAVE + lane;
        vint4 v0 = __builtin_nontemporal_load(yp4 + base + 0 * 64);
        vint4 v1 = __builtin_nontemporal_load(yp4 + base + 1 * 64);
        vint4 v2 = __builtin_nontemporal_load(yp4 + base + 2 * 64);
        vint4 v3 = __builtin_nontemporal_load(yp4 + base + 3 * 64);
        vint4 v4 = __builtin_nontemporal_load(yp4 + base + 4 * 64);
        vint4 v5 = __builtin_nontemporal_load(yp4 + base + 5 * 64);
        vint4 v6 = __builtin_nontemporal_load(yp4 + base + 6 * 64);
        vint4 v7 = __builtin_nontemporal_load(yp4 + base + 7 * 64);
        m  = (1u << v0.x) | (1u << v0.y) | (1u << v0.z) | (1u << v0.w);
        m |= (1u << v1.x) | (1u << v1.y) | (1u << v1.z) | (1u << v1.w);
        m |= (1u << v2.x) | (1u << v2.y) | (1u << v2.z) | (1u << v2.w);
        m |= (1u << v3.x) | (1u << v3.y) | (1u << v3.z) | (1u << v3.w);
        m |= (1u << v4.x) | (1u << v4.y) | (1u << v4.z) | (1u << v4.w);
        m |= (1u << v5.x) | (1u << v5.y) | (1u << v5.z) | (1u << v5.w);
        m |= (1u << v6.x) | (1u << v6.y) | (1u << v6.z) | (1u << v6.w);
        m |= (1u << v7.x) | (1u << v7.y) | (1u << v7.z) | (1u << v7.w);
    } else {
        const int idx = blockIdx.x * blockDim.x + threadIdx.x;
        const int stride = gridDim.x * blockDim.x;
        for (int i = idx; i < n4; i += stride) {
            vint4 v = __builtin_nontemporal_load(yp4 + i);
            m |= (1u << v.x) | (1u << v.y) | (1u << v.z) | (1u << v.w);
        }
    }

    // wave-64 OR butterfly
    #pragma unroll
    for (int off = 32; off >= 1; off >>= 1) {
        m |= __shfl_xor(m, off, 64);
    }
    __shared__ unsigned int wmask[WAVES_PER_BLOCK];
    if (lane == 0) {
        wmask[wave_in_block] = m;
    }
    __syncthreads();
    if (threadIdx.x == 0) {
        block_masks[blockIdx.x] = wmask[0] | wmask[1] | wmask[2] | wmask[3];
    }
}

__global__ __launch_bounds__(256) void miou_finalize(
        const unsigned int* __restrict__ block_masks,
        float* __restrict__ out,
        int nblocks) {
    unsigned int m = 0u;
    for (int i = threadIdx.x; i < nblocks; i += blockDim.x) {
        m |= block_masks[i];
    }
    #pragma unroll
    for (int off = 32; off >= 1; off >>= 1) {
        m |= __shfl_xor(m, off, 64);
    }
    __shared__ unsigned int wmask[4];
    if ((threadIdx.x & 63) == 0) {
        wmask[threadIdx.x >> 6] = m;
    }
    __syncthreads();
    if (threadIdx.x == 0) {
        unsigned int t = (wmask[0] | wmask[1] | wmask[2] | wmask[3]) & 0x001FFFFEu;
        out[0] = (float)__popc(t) / (float)NUM_CLASSES;
    }
}

extern "C" void kernel_launch(void* const* d_in, const int* in_sizes, int n_in,
                              void* d_out, int out_size, void* d_ws, size_t ws_size,
                              hipStream_t stream) {
    const int* y_pred = (const int*)d_in[0];
    // d_in[1] (y_true) is dead in the reference.
    float* out = (float*)d_out;
    unsigned int* block_masks = (unsigned int*)d_ws;  // SCAN_GRID dwords

    int n = in_sizes[0];   // 16,777,216
    int n4 = n >> 2;

    miou_scan<<<SCAN_GRID, SCAN_BLOCK, 0, stream>>>(y_pred, block_masks, n4);
    miou_finalize<<<1, 256, 0, stream>>>(block_masks, out, SCAN_GRID);
}

// Round 7
// 118.848 us; speedup vs baseline: 1.8404x; 1.0805x over previous
//
#include <hip/hip_runtime.h>
#include <hip/hip_bf16.h>

// MIoU (buggy-source-faithful): result = popcount(classes 1..20 present in y_pred) / 21.
// y_true is dead in the reference. Presence scan over 64 MiB of int32.
//
// R1: same-address atomicOr serialized (~31 cyc/op) -> 107 us scan.
// R2: atomic-free -> total 134 us; scan ~22 us (3.2 TB/s read).
// R3: flat 4-load neutral -> not load-issue-bound.
// R4: wave-contiguous single-pass neutral -> memory-path ceiling.
// R6: nt loads WIN (-4 us): part of the cap was L2-allocate churn.
// R7: algorithmic short-circuit. Probe kernel scans first 64 KB; if classes
//   1..20 all present (certain for uniform-random data), writes 20/21 and a
//   flag; scan+finalize early-exit on the flag. Exact for any input: full
//   nt-load scan still runs when the prefix is inconclusive. Kernel
//   boundaries on one stream provide cross-XCD visibility for the flag.

#define NUM_CLASSES 21
#define FULL_MASK 0x001FFFFEu   // bits 1..20
#define SCAN_GRID 2048
#define SCAN_BLOCK 256
#define WAVES_PER_BLOCK (SCAN_BLOCK / 64)
#define VEC_PER_WAVE 512        // 8 loads x 64 lanes, int4 units (32 KB/wave)
#define PROBE_INTS 16384        // 64 KB prefix; P(class missing) ~ 1e-338

typedef int vint4 __attribute__((ext_vector_type(4)));

__device__ __forceinline__ unsigned int block_or_reduce(unsigned int m,
                                                        unsigned int* wmask) {
    #pragma unroll
    for (int off = 32; off >= 1; off >>= 1) {
        m |= __shfl_xor(m, off, 64);
    }
    if ((threadIdx.x & 63) == 0) {
        wmask[threadIdx.x >> 6] = m;
    }
    __syncthreads();
    return wmask[0] | wmask[1] | wmask[2] | wmask[3];
}

__global__ __launch_bounds__(256) void miou_probe(
        const int* __restrict__ yp, int n,
        unsigned int* __restrict__ flag, float* __restrict__ out) {
    const vint4* __restrict__ yp4 = (const vint4*)yp;
    unsigned int m = 0u;
    if (n >= PROBE_INTS) {
        const int t = threadIdx.x;
        #pragma unroll
        for (int k = 0; k < PROBE_INTS / (4 * 256); ++k) {
            vint4 v = yp4[t + k * 256];
            m |= (1u << v.x) | (1u << v.y) | (1u << v.z) | (1u << v.w);
        }
    }
    __shared__ unsigned int wmask[4];
    unsigned int all = block_or_reduce(m, wmask);
    if (threadIdx.x == 0) {
        if ((all & FULL_MASK) == FULL_MASK) {
            out[0] = (float)__popc(FULL_MASK) / (float)NUM_CLASSES;
            *flag = 1u;
        } else {
            *flag = 0u;
        }
    }
}

__global__ __launch_bounds__(SCAN_BLOCK) void miou_scan(
        const int* __restrict__ yp,
        const unsigned int* __restrict__ flag,
        unsigned int* __restrict__ block_masks,
        int n4) {
    if (*flag) return;   // answer already decided by the probe

    const vint4* __restrict__ yp4 = (const vint4*)yp;
    const int lane = threadIdx.x & 63;
    const int wave_in_block = threadIdx.x >> 6;
    const int gwave = blockIdx.x * WAVES_PER_BLOCK + wave_in_block;
    unsigned int m = 0u;

    if (n4 == SCAN_GRID * WAVES_PER_BLOCK * VEC_PER_WAVE) {
        const int base = gwave * VEC_PER_WAVE + lane;
        vint4 v0 = __builtin_nontemporal_load(yp4 + base + 0 * 64);
        vint4 v1 = __builtin_nontemporal_load(yp4 + base + 1 * 64);
        vint4 v2 = __builtin_nontemporal_load(yp4 + base + 2 * 64);
        vint4 v3 = __builtin_nontemporal_load(yp4 + base + 3 * 64);
        vint4 v4 = __builtin_nontemporal_load(yp4 + base + 4 * 64);
        vint4 v5 = __builtin_nontemporal_load(yp4 + base + 5 * 64);
        vint4 v6 = __builtin_nontemporal_load(yp4 + base + 6 * 64);
        vint4 v7 = __builtin_nontemporal_load(yp4 + base + 7 * 64);
        m  = (1u << v0.x) | (1u << v0.y) | (1u << v0.z) | (1u << v0.w);
        m |= (1u << v1.x) | (1u << v1.y) | (1u << v1.z) | (1u << v1.w);
        m |= (1u << v2.x) | (1u << v2.y) | (1u << v2.z) | (1u << v2.w);
        m |= (1u << v3.x) | (1u << v3.y) | (1u << v3.z) | (1u << v3.w);
        m |= (1u << v4.x) | (1u << v4.y) | (1u << v4.z) | (1u << v4.w);
        m |= (1u << v5.x) | (1u << v5.y) | (1u << v5.z) | (1u << v5.w);
        m |= (1u << v6.x) | (1u << v6.y) | (1u << v6.z) | (1u << v6.w);
        m |= (1u << v7.x) | (1u << v7.y) | (1u << v7.z) | (1u << v7.w);
    } else {
        const int idx = blockIdx.x * blockDim.x + threadIdx.x;
        const int stride = gridDim.x * blockDim.x;
        for (int i = idx; i < n4; i += stride) {
            vint4 v = __builtin_nontemporal_load(yp4 + i);
            m |= (1u << v.x) | (1u << v.y) | (1u << v.z) | (1u << v.w);
        }
    }

    __shared__ unsigned int wmask[WAVES_PER_BLOCK];
    unsigned int all = block_or_reduce(m, wmask);
    if (threadIdx.x == 0) {
        block_masks[blockIdx.x] = all;
    }
}

__global__ __launch_bounds__(256) void miou_finalize(
        const unsigned int* __restrict__ flag,
        const unsigned int* __restrict__ block_masks,
        float* __restrict__ out,
        int nblocks) {
    if (*flag) return;   // probe already wrote the answer

    unsigned int m = 0u;
    for (int i = threadIdx.x; i < nblocks; i += blockDim.x) {
        m |= block_masks[i];
    }
    __shared__ unsigned int wmask[4];
    unsigned int all = block_or_reduce(m, wmask);
    if (threadIdx.x == 0) {
        out[0] = (float)__popc(all & FULL_MASK) / (float)NUM_CLASSES;
    }
}

extern "C" void kernel_launch(void* const* d_in, const int* in_sizes, int n_in,
                              void* d_out, int out_size, void* d_ws, size_t ws_size,
                              hipStream_t stream) {
    const int* y_pred = (const int*)d_in[0];
    // d_in[1] (y_true) is dead in the reference.
    float* out = (float*)d_out;
    unsigned int* flag = (unsigned int*)d_ws;                // 1 dword
    unsigned int* block_masks = (unsigned int*)d_ws + 16;    // SCAN_GRID dwords

    int n = in_sizes[0];   // 16,777,216
    int n4 = n >> 2;

    miou_probe<<<1, 256, 0, stream>>>(y_pred, n, flag, out);
    miou_scan<<<SCAN_GRID, SCAN_BLOCK, 0, stream>>>(y_pred, flag, block_masks, n4);
    miou_finalize<<<1, 256, 0, stream>>>(flag, block_masks, out, SCAN_GRID);
}